// Round 1
// baseline (244.188 us; speedup 1.0000x reference)
//
#include <hip/hip_runtime.h>

typedef __attribute__((ext_vector_type(8))) short short8;
typedef __attribute__((ext_vector_type(4))) float f32x4;

#define N_NODES 4096
#define N_FEAT  256

__device__ __forceinline__ unsigned short f2bf(float f) {
  union { float f; unsigned u; } a; a.f = f;
  unsigned r = a.u + 0x7FFFu + ((a.u >> 16) & 1u);  // round-to-nearest-even
  return (unsigned short)(r >> 16);
}

__device__ __forceinline__ void gload_lds16(const void* g, void* l) {
  __builtin_amdgcn_global_load_lds(
      (const __attribute__((address_space(1))) void*)g,
      (__attribute__((address_space(3))) void*)l, 16, 0, 0);
}

// ---------------------------------------------------------------- spectrum
__global__ void spectrum_k(const float* __restrict__ lam, const float* __restrict__ tp,
                           float* __restrict__ cbuf, float* __restrict__ p2buf) {
  int i = blockIdx.x * 256 + threadIdx.x;
  float tv = tp[0];
  float s = sqrtf(fmaxf(lam[i], 0.f));
  cbuf[i] = cosf(tv * s);
  p2buf[i] = (s < 1e-5f) ? tv : (sinf(tv * s) / s);
}

// ------------------------------------------- V -> Vbf (bf16) + Vt (bf16, transposed)
__global__ __launch_bounds__(256) void prep_v_k(const float* __restrict__ V,
                                                unsigned short* __restrict__ Vbf,
                                                unsigned short* __restrict__ Vt) {
  __shared__ unsigned short tile[64][68];
  int t = threadIdx.x;
  int r = t >> 2;            // 0..63 row in tile
  int cs = (t & 3) * 16;     // col segment
  int gr = blockIdx.y * 64 + r;
  int gc0 = blockIdx.x * 64;
#pragma unroll
  for (int i = 0; i < 4; ++i) {
    int c = cs + i * 4;
    float4 v = *(const float4*)&V[(size_t)gr * N_NODES + gc0 + c];
    unsigned short h0 = f2bf(v.x), h1 = f2bf(v.y), h2 = f2bf(v.z), h3 = f2bf(v.w);
    ushort4 u; u.x = h0; u.y = h1; u.z = h2; u.w = h3;
    *(ushort4*)&Vbf[(size_t)gr * N_NODES + gc0 + c] = u;
    tile[c + 0][r] = h0; tile[c + 1][r] = h1; tile[c + 2][r] = h2; tile[c + 3][r] = h3;
  }
  __syncthreads();
#pragma unroll
  for (int i = 0; i < 4; ++i) {
    int rr = cs + i * 4;  // original-row group
    ushort4 u = *(ushort4*)&tile[r][rr];
    *(ushort4*)&Vt[(size_t)(gc0 + r) * N_NODES + blockIdx.y * 64 + rr] = u;
  }
}

// ------------------------------ x,y -> S2T[512][4096] bf16: S2T[2f+s][j] = (s?y:x)[j][f]
__global__ __launch_bounds__(256) void prep_xy_k(const float* __restrict__ x,
                                                 const float* __restrict__ y,
                                                 unsigned short* __restrict__ S2T) {
  __shared__ unsigned short tx[64][68];
  __shared__ unsigned short ty[64][68];
  int t = threadIdx.x;
  int jl = t >> 2;
  int fs = (t & 3) * 16;
  int gj = blockIdx.y * 64 + jl;
  int gf0 = blockIdx.x * 64;
#pragma unroll
  for (int i = 0; i < 4; ++i) {
    int f = fs + i * 4;
    float4 vx = *(const float4*)&x[(size_t)gj * N_FEAT + gf0 + f];
    float4 vy = *(const float4*)&y[(size_t)gj * N_FEAT + gf0 + f];
    tx[f + 0][jl] = f2bf(vx.x); tx[f + 1][jl] = f2bf(vx.y);
    tx[f + 2][jl] = f2bf(vx.z); tx[f + 3][jl] = f2bf(vx.w);
    ty[f + 0][jl] = f2bf(vy.x); ty[f + 1][jl] = f2bf(vy.y);
    ty[f + 2][jl] = f2bf(vy.z); ty[f + 3][jl] = f2bf(vy.w);
  }
  __syncthreads();
  int fl = t >> 2;
#pragma unroll
  for (int i = 0; i < 4; ++i) {
    int j4 = fs + i * 4;
    ushort4 ux = *(ushort4*)&tx[fl][j4];
    ushort4 uy = *(ushort4*)&ty[fl][j4];
    int gf = gf0 + fl;
    *(ushort4*)&S2T[(size_t)(2 * gf + 0) * N_NODES + blockIdx.y * 64 + j4] = ux;
    *(ushort4*)&S2T[(size_t)(2 * gf + 1) * N_NODES + blockIdx.y * 64 + j4] = uy;
  }
}

// --------------------------------------------------------------- GEMM
// C[M,N] = A'[M,K] * B'[N,K]^T   (both operands row-major with K contiguous)
// BM=128, BN=64, BK=32, 256 threads (4 waves, 2x2), per-wave 64x32 (4x2 frags).
// EPI==0: gemm1 -> fused spectral scale, writes Zt[f][m] bf16 (outp), n-pairs are (x,y)
// EPI==1: gemm2 -> writes out[m][f] f32
template <int EPI>
__global__ __launch_bounds__(256) void gemm_k(const unsigned short* __restrict__ A,
                                              const unsigned short* __restrict__ B,
                                              const float* __restrict__ cbuf,
                                              const float* __restrict__ p2buf,
                                              void* __restrict__ outp) {
  __shared__ unsigned short As[128 * 32];
  __shared__ unsigned short Bs[64 * 32];
  const int t = threadIdx.x;
  const int mtile = blockIdx.y, ntile = blockIdx.x;
  const int lane = t & 63, wv = t >> 6;
  const int wr = (wv >> 1) * 64;
  const int wc = (wv & 1) * 32;
  const int l15 = lane & 15;
  const int lk = (lane >> 4) * 8;

  const unsigned short* Ag = A + ((size_t)(mtile * 128 + (t >> 2)) * N_NODES + (t & 3) * 8);
  const unsigned short* Bg = B + ((size_t)(ntile * 64 + (t >> 2)) * N_NODES + (t & 3) * 8);

  f32x4 acc[4][2];
#pragma unroll
  for (int mi = 0; mi < 4; ++mi)
#pragma unroll
    for (int ni = 0; ni < 2; ++ni) acc[mi][ni] = (f32x4){0.f, 0.f, 0.f, 0.f};

  for (int kt = 0; kt < N_NODES / 32; ++kt) {
    gload_lds16(Ag + kt * 32, &As[t * 8]);
    gload_lds16(Ag + kt * 32 + (size_t)64 * N_NODES, &As[2048 + t * 8]);
    gload_lds16(Bg + kt * 32, &Bs[t * 8]);
    __syncthreads();
    short8 a[4], b[2];
#pragma unroll
    for (int mi = 0; mi < 4; ++mi)
      a[mi] = *(const short8*)&As[(wr + mi * 16 + l15) * 32 + lk];
#pragma unroll
    for (int ni = 0; ni < 2; ++ni)
      b[ni] = *(const short8*)&Bs[(wc + ni * 16 + l15) * 32 + lk];
#pragma unroll
    for (int mi = 0; mi < 4; ++mi)
#pragma unroll
      for (int ni = 0; ni < 2; ++ni)
        acc[mi][ni] = __builtin_amdgcn_mfma_f32_16x16x32_bf16(a[mi], b[ni], acc[mi][ni], 0, 0, 0);
    __syncthreads();
  }

  const int m0base = mtile * 128 + wr + (lane >> 4) * 4;
  if (EPI == 0) {
    unsigned short* Zt = (unsigned short*)outp;
    const int nbase = ntile * 64 + wc + l15;
#pragma unroll
    for (int mi = 0; mi < 4; ++mi) {
      const int m0 = m0base + mi * 16;
      f32x4 cv = *(const f32x4*)&cbuf[m0];
      f32x4 pv = *(const f32x4*)&p2buf[m0];
#pragma unroll
      for (int ni = 0; ni < 2; ++ni) {
        const int n = nbase + ni * 16;
        float z[4];
#pragma unroll
        for (int r = 0; r < 4; ++r) {
          float own = acc[mi][ni][r];
          float oth = __shfl_xor(own, 1);
          float dx = (n & 1) ? oth : own;   // x-path (even n)
          float dy = (n & 1) ? own : oth;   // y-path (odd n)
          z[r] = cv[r] * dx + pv[r] * dy;
        }
        if ((lane & 1) == 0) {
          int f = n >> 1;
          ushort4 u; u.x = f2bf(z[0]); u.y = f2bf(z[1]); u.z = f2bf(z[2]); u.w = f2bf(z[3]);
          *(ushort4*)&Zt[(size_t)f * N_NODES + m0] = u;
        }
      }
    }
  } else {
    float* out = (float*)outp;
#pragma unroll
    for (int mi = 0; mi < 4; ++mi)
#pragma unroll
      for (int ni = 0; ni < 2; ++ni) {
        const int f = ntile * 64 + wc + ni * 16 + l15;
#pragma unroll
        for (int r = 0; r < 4; ++r)
          out[(size_t)(m0base + mi * 16 + r) * N_FEAT + f] = acc[mi][ni][r];
      }
  }
}

extern "C" void kernel_launch(void* const* d_in, const int* in_sizes, int n_in,
                              void* d_out, int out_size, void* d_ws, size_t ws_size,
                              hipStream_t stream) {
  const float* x   = (const float*)d_in[0];
  const float* y   = (const float*)d_in[1];
  const float* tp  = (const float*)d_in[2];
  const float* lam = (const float*)d_in[3];
  const float* V   = (const float*)d_in[4];

  char* w = (char*)d_ws;
  unsigned short* Vbf  = (unsigned short*)w; w += (size_t)N_NODES * N_NODES * 2;
  unsigned short* Vtbf = (unsigned short*)w; w += (size_t)N_NODES * N_NODES * 2;
  unsigned short* S2T  = (unsigned short*)w; w += (size_t)512 * N_NODES * 2;
  unsigned short* Zt   = (unsigned short*)w; w += (size_t)N_FEAT * N_NODES * 2;
  float* cbuf  = (float*)w; w += N_NODES * 4;
  float* p2buf = (float*)w; w += N_NODES * 4;

  spectrum_k<<<N_NODES / 256, 256, 0, stream>>>(lam, tp, cbuf, p2buf);
  prep_v_k<<<dim3(N_NODES / 64, N_NODES / 64), 256, 0, stream>>>(V, Vbf, Vtbf);
  prep_xy_k<<<dim3(N_FEAT / 64, N_NODES / 64), 256, 0, stream>>>(x, y, S2T);
  // GEMM1: A=Vt [4096,4096], B=S2T [512,4096] -> Zt [256][4096] bf16 (fused scale)
  gemm_k<0><<<dim3(512 / 64, N_NODES / 128), 256, 0, stream>>>(Vtbf, S2T, cbuf, p2buf, Zt);
  // GEMM2: A=Vbf [4096,4096], B=Zt [256,4096] -> out [4096,256] f32
  gemm_k<1><<<dim3(N_FEAT / 64, N_NODES / 128), 256, 0, stream>>>(Vbf, Zt, cbuf, p2buf, d_out);
}

// Round 2
// 226.963 us; speedup vs baseline: 1.0759x; 1.0759x over previous
//
#include <hip/hip_runtime.h>

typedef __attribute__((ext_vector_type(8))) short short8;
typedef __attribute__((ext_vector_type(8))) unsigned short ushort8v;
typedef __attribute__((ext_vector_type(4))) float f32x4;

#define N_NODES 4096
#define N_FEAT  256

__device__ __forceinline__ unsigned short f2bf(float f) {
  union { float f; unsigned u; } a; a.f = f;
  unsigned r = a.u + 0x7FFFu + ((a.u >> 16) & 1u);  // round-to-nearest-even
  return (unsigned short)(r >> 16);
}

__device__ __forceinline__ void gload_lds16(const void* g, void* l) {
  __builtin_amdgcn_global_load_lds(
      (const __attribute__((address_space(1))) void*)g,
      (__attribute__((address_space(3))) void*)l, 16, 0, 0);
}

// ---------------------------------------------------------------- spectrum
__global__ void spectrum_k(const float* __restrict__ lam, const float* __restrict__ tp,
                           float* __restrict__ cbuf, float* __restrict__ p2buf) {
  int i = blockIdx.x * 256 + threadIdx.x;
  float tv = tp[0];
  float s = sqrtf(fmaxf(lam[i], 0.f));
  cbuf[i] = cosf(tv * s);
  p2buf[i] = (s < 1e-5f) ? tv : (sinf(tv * s) / s);
}

// ------------------------------------------- V -> Vbf (bf16) + Vt (bf16, transposed)
// 64x64 tile; load col = q*4+i*16 (64B segments); tile pad 72 (16B-aligned rows,
// write banks (16q+4j+r>>1)%32 -> <=4-way); transposed 16B stores, 64B/4-lane groups.
__global__ __launch_bounds__(256) void prep_v_k(const float* __restrict__ V,
                                                unsigned short* __restrict__ Vbf,
                                                unsigned short* __restrict__ Vt) {
  __shared__ unsigned short tile[64][72];
  const int t = threadIdx.x;
  const int r = t >> 2, q = t & 3;
  const int gr = blockIdx.y * 64 + r;
  const int gc0 = blockIdx.x * 64;
#pragma unroll
  for (int i = 0; i < 4; ++i) {
    int c = q * 4 + i * 16;
    float4 v = *(const float4*)&V[(size_t)gr * N_NODES + gc0 + c];
    ushort4 u; u.x = f2bf(v.x); u.y = f2bf(v.y); u.z = f2bf(v.z); u.w = f2bf(v.w);
    *(ushort4*)&Vbf[(size_t)gr * N_NODES + gc0 + c] = u;
    tile[c + 0][r] = u.x; tile[c + 1][r] = u.y; tile[c + 2][r] = u.z; tile[c + 3][r] = u.w;
  }
  __syncthreads();
  const int r2 = t >> 2;  // transposed row = V column
#pragma unroll
  for (int j = 0; j < 2; ++j) {
    int ms = q * 8 + j * 32;
    ushort8v u = *(const ushort8v*)&tile[r2][ms];
    *(ushort8v*)&Vt[(size_t)(gc0 + r2) * N_NODES + blockIdx.y * 64 + ms] = u;
  }
}

// ------------------------------ x,y -> S2T[512][4096] bf16: S2T[2f+s][j] = (s?y:x)[j][f]
__global__ __launch_bounds__(256) void prep_xy_k(const float* __restrict__ x,
                                                 const float* __restrict__ y,
                                                 unsigned short* __restrict__ S2T) {
  __shared__ unsigned short tx[64][72];
  __shared__ unsigned short ty[64][72];
  const int t = threadIdx.x;
  const int r = t >> 2, q = t & 3;
  const int gj = blockIdx.y * 64 + r;
  const int gf0 = blockIdx.x * 64;
#pragma unroll
  for (int i = 0; i < 4; ++i) {
    int c = q * 4 + i * 16;
    float4 vx = *(const float4*)&x[(size_t)gj * N_FEAT + gf0 + c];
    float4 vy = *(const float4*)&y[(size_t)gj * N_FEAT + gf0 + c];
    tx[c + 0][r] = f2bf(vx.x); tx[c + 1][r] = f2bf(vx.y);
    tx[c + 2][r] = f2bf(vx.z); tx[c + 3][r] = f2bf(vx.w);
    ty[c + 0][r] = f2bf(vy.x); ty[c + 1][r] = f2bf(vy.y);
    ty[c + 2][r] = f2bf(vy.z); ty[c + 3][r] = f2bf(vy.w);
  }
  __syncthreads();
  const int f2 = t >> 2;
#pragma unroll
  for (int j = 0; j < 2; ++j) {
    int js = q * 8 + j * 32;
    ushort8v ux = *(const ushort8v*)&tx[f2][js];
    ushort8v uy = *(const ushort8v*)&ty[f2][js];
    *(ushort8v*)&S2T[(size_t)(2 * (gf0 + f2) + 0) * N_NODES + blockIdx.y * 64 + js] = ux;
    *(ushort8v*)&S2T[(size_t)(2 * (gf0 + f2) + 1) * N_NODES + blockIdx.y * 64 + js] = uy;
  }
}

// --------------------------------------------------------------- split-K GEMM
// Cpart[z][M,N] = A[M, z*Kc : (z+1)*Kc] * B[N, same]^T ; A,B row-major K-contiguous bf16.
// BM=128, BN=64, BK=32, 256 threads (4 waves 2x2), wave tile 64x32 (4x2 frags).
__global__ __launch_bounds__(256) void gemm_split_k(const unsigned short* __restrict__ A,
                                                    const unsigned short* __restrict__ B,
                                                    float* __restrict__ part,
                                                    int K, int Kc, int Nn, size_t MN) {
  __shared__ unsigned short As[128 * 32];
  __shared__ unsigned short Bs[64 * 32];
  const int t = threadIdx.x;
  const int lane = t & 63, wv = t >> 6;
  const int wr = (wv >> 1) * 64;
  const int wc = (wv & 1) * 32;
  const int l15 = lane & 15;
  const int lk = (lane >> 4) * 8;
  const size_t kbase = (size_t)blockIdx.z * Kc;

  const unsigned short* Ag = A + ((size_t)(blockIdx.y * 128 + (t >> 2))) * K + kbase + (t & 3) * 8;
  const unsigned short* Bg = B + ((size_t)(blockIdx.x * 64 + (t >> 2))) * K + kbase + (t & 3) * 8;

  f32x4 acc[4][2];
#pragma unroll
  for (int mi = 0; mi < 4; ++mi)
#pragma unroll
    for (int ni = 0; ni < 2; ++ni) acc[mi][ni] = (f32x4){0.f, 0.f, 0.f, 0.f};

  const int nkt = Kc >> 5;
  for (int kt = 0; kt < nkt; ++kt) {
    gload_lds16(Ag + kt * 32, &As[t * 8]);
    gload_lds16(Ag + kt * 32 + (size_t)64 * K, &As[2048 + t * 8]);
    gload_lds16(Bg + kt * 32, &Bs[t * 8]);
    __syncthreads();
    short8 a[4], b[2];
#pragma unroll
    for (int mi = 0; mi < 4; ++mi)
      a[mi] = *(const short8*)&As[(wr + mi * 16 + l15) * 32 + lk];
#pragma unroll
    for (int ni = 0; ni < 2; ++ni)
      b[ni] = *(const short8*)&Bs[(wc + ni * 16 + l15) * 32 + lk];
#pragma unroll
    for (int mi = 0; mi < 4; ++mi)
#pragma unroll
      for (int ni = 0; ni < 2; ++ni)
        acc[mi][ni] = __builtin_amdgcn_mfma_f32_16x16x32_bf16(a[mi], b[ni], acc[mi][ni], 0, 0, 0);
    __syncthreads();
  }

  float* po = part + (size_t)blockIdx.z * MN;
  const int m0 = blockIdx.y * 128 + wr + (lane >> 4) * 4;
  const int n0 = blockIdx.x * 64 + wc + l15;
#pragma unroll
  for (int mi = 0; mi < 4; ++mi)
#pragma unroll
    for (int ni = 0; ni < 2; ++ni)
#pragma unroll
      for (int r = 0; r < 4; ++r)
        po[(size_t)(m0 + mi * 16 + r) * Nn + n0 + ni * 16] = acc[mi][ni][r];
}

// --------------- reduce1: Zt[f][m] = c[m]*sum_ks part[ks][m][2f] + p2[m]*sum_ks part[ks][m][2f+1]
// block: 64 m (blockIdx.y) x 128 n = 64 f (blockIdx.x); LDS transpose; 16B coalesced stores.
__global__ __launch_bounds__(256) void reduce1_k(const float* __restrict__ part,
                                                 const float* __restrict__ cbuf,
                                                 const float* __restrict__ p2buf,
                                                 unsigned short* __restrict__ Zt) {
  __shared__ unsigned short zt[64][72];
  const int t = threadIdx.x;
  const int r = t >> 2, q = t & 3;
  const int m = blockIdx.y * 64 + r;
  const int n0 = blockIdx.x * 128;
  const float cv = cbuf[m], pv = p2buf[m];
  float acc[16];
#pragma unroll
  for (int i = 0; i < 16; ++i) acc[i] = 0.f;
  for (int ks = 0; ks < 4; ++ks) {
    const float* p = part + ((size_t)ks * N_NODES + m) * 512 + n0;
#pragma unroll
    for (int i = 0; i < 8; ++i) {
      float4 v = *(const float4*)&p[q * 4 + i * 16];  // (x_f, y_f, x_{f+1}, y_{f+1})
      acc[2 * i + 0] += cv * v.x + pv * v.y;
      acc[2 * i + 1] += cv * v.z + pv * v.w;
    }
  }
#pragma unroll
  for (int i = 0; i < 8; ++i) {
    int f = q * 2 + i * 8;  // f index within block (c/2 where c = q*4+i*16)
    zt[f + 0][r] = f2bf(acc[2 * i + 0]);
    zt[f + 1][r] = f2bf(acc[2 * i + 1]);
  }
  __syncthreads();
  const int f2 = t >> 2;
  const int gf = blockIdx.x * 64 + f2;
#pragma unroll
  for (int w = 0; w < 2; ++w) {
    int js = q * 8 + w * 32;
    ushort8v u = *(const ushort8v*)&zt[f2][js];
    *(ushort8v*)&Zt[(size_t)gf * N_NODES + blockIdx.y * 64 + js] = u;
  }
}

// --------------- reduce2: out[e] = sum_{ks<8} part[ks][e]
__global__ __launch_bounds__(256) void reduce2_k(const float* __restrict__ part,
                                                 float* __restrict__ out) {
  const size_t e = ((size_t)blockIdx.x * 256 + threadIdx.x) * 4;
  float4 s = {0.f, 0.f, 0.f, 0.f};
#pragma unroll
  for (int ks = 0; ks < 8; ++ks) {
    float4 v = *(const float4*)&part[(size_t)ks * N_NODES * N_FEAT + e];
    s.x += v.x; s.y += v.y; s.z += v.z; s.w += v.w;
  }
  *(float4*)&out[e] = s;
}

extern "C" void kernel_launch(void* const* d_in, const int* in_sizes, int n_in,
                              void* d_out, int out_size, void* d_ws, size_t ws_size,
                              hipStream_t stream) {
  const float* x   = (const float*)d_in[0];
  const float* y   = (const float*)d_in[1];
  const float* tp  = (const float*)d_in[2];
  const float* lam = (const float*)d_in[3];
  const float* V   = (const float*)d_in[4];

  char* w = (char*)d_ws;
  unsigned short* Vbf  = (unsigned short*)w; w += (size_t)N_NODES * N_NODES * 2;
  unsigned short* Vtbf = (unsigned short*)w; w += (size_t)N_NODES * N_NODES * 2;
  unsigned short* S2T  = (unsigned short*)w; w += (size_t)512 * N_NODES * 2;
  unsigned short* Zt   = (unsigned short*)w; w += (size_t)N_FEAT * N_NODES * 2;
  float* cbuf  = (float*)w; w += N_NODES * 4;
  float* p2buf = (float*)w; w += N_NODES * 4;
  float* partb = (float*)w; w += (size_t)4 * N_NODES * 512 * 4;  // 33.5MB, shared by both stages

  spectrum_k<<<N_NODES / 256, 256, 0, stream>>>(lam, tp, cbuf, p2buf);
  prep_v_k<<<dim3(N_NODES / 64, N_NODES / 64), 256, 0, stream>>>(V, Vbf, Vtbf);
  prep_xy_k<<<dim3(N_FEAT / 64, N_NODES / 64), 256, 0, stream>>>(x, y, S2T);
  // GEMM1: Z_part[ks][i][s] = Vt[i, ks-chunk] . S2T[s, ks-chunk]   (ksplit=4, Kc=1024)
  gemm_split_k<<<dim3(512 / 64, N_NODES / 128, 4), 256, 0, stream>>>(
      Vtbf, S2T, partb, N_NODES, 1024, 512, (size_t)N_NODES * 512);
  // reduce1: spectral scale + transpose -> Zt[f][i] bf16
  reduce1_k<<<dim3(512 / 128, N_NODES / 64), 256, 0, stream>>>(partb, cbuf, p2buf, Zt);
  // GEMM2: out_part[ks][j][f] = Vbf[j, ks-chunk] . Zt[f, ks-chunk]  (ksplit=8, Kc=512)
  gemm_split_k<<<dim3(N_FEAT / 64, N_NODES / 128, 8), 256, 0, stream>>>(
      Vbf, Zt, partb, N_NODES, 512, N_FEAT, (size_t)N_NODES * N_FEAT);
  // reduce2: plain 8-way sum -> out f32
  reduce2_k<<<(N_NODES * N_FEAT) / 1024, 256, 0, stream>>>(partb, (float*)d_out);
}

// Round 3
// 178.389 us; speedup vs baseline: 1.3688x; 1.2723x over previous
//
#include <hip/hip_runtime.h>

typedef __attribute__((ext_vector_type(8))) short short8;
typedef __attribute__((ext_vector_type(8))) unsigned short ushort8v;
typedef __attribute__((ext_vector_type(4))) float f32x4;

#define N_NODES 4096
#define N_FEAT  256

__device__ __forceinline__ unsigned short f2bf(float f) {
  union { float f; unsigned u; } a; a.f = f;
  unsigned r = a.u + 0x7FFFu + ((a.u >> 16) & 1u);  // round-to-nearest-even
  return (unsigned short)(r >> 16);
}

__device__ __forceinline__ void gload_lds16(const void* g, void* l) {
  __builtin_amdgcn_global_load_lds(
      (const __attribute__((address_space(1))) void*)g,
      (__attribute__((address_space(3))) void*)l, 16, 0, 0);
}

// ---------------------------------------------------------------- spectrum
__global__ void spectrum_k(const float* __restrict__ lam, const float* __restrict__ tp,
                           float* __restrict__ cbuf, float* __restrict__ p2buf) {
  int i = blockIdx.x * 256 + threadIdx.x;
  float tv = tp[0];
  float s = sqrtf(fmaxf(lam[i], 0.f));
  cbuf[i] = cosf(tv * s);
  p2buf[i] = (s < 1e-5f) ? tv : (sinf(tv * s) / s);
}

// ------------------------------------------- V -> Vbf (bf16) + Vt (bf16, transposed)
__global__ __launch_bounds__(256) void prep_v_k(const float* __restrict__ V,
                                                unsigned short* __restrict__ Vbf,
                                                unsigned short* __restrict__ Vt) {
  __shared__ unsigned short tile[64][72];
  const int t = threadIdx.x;
  const int r = t >> 2, q = t & 3;
  const int gr = blockIdx.y * 64 + r;
  const int gc0 = blockIdx.x * 64;
#pragma unroll
  for (int i = 0; i < 4; ++i) {
    int c = q * 4 + i * 16;
    float4 v = *(const float4*)&V[(size_t)gr * N_NODES + gc0 + c];
    ushort4 u; u.x = f2bf(v.x); u.y = f2bf(v.y); u.z = f2bf(v.z); u.w = f2bf(v.w);
    *(ushort4*)&Vbf[(size_t)gr * N_NODES + gc0 + c] = u;
    tile[c + 0][r] = u.x; tile[c + 1][r] = u.y; tile[c + 2][r] = u.z; tile[c + 3][r] = u.w;
  }
  __syncthreads();
  const int r2 = t >> 2;  // transposed row = V column
#pragma unroll
  for (int j = 0; j < 2; ++j) {
    int ms = q * 8 + j * 32;
    ushort8v u = *(const ushort8v*)&tile[r2][ms];
    *(ushort8v*)&Vt[(size_t)(gc0 + r2) * N_NODES + blockIdx.y * 64 + ms] = u;
  }
}

// ------------------------------ x,y -> S2T[512][4096] bf16: S2T[2f+s][j] = (s?y:x)[j][f]
__global__ __launch_bounds__(256) void prep_xy_k(const float* __restrict__ x,
                                                 const float* __restrict__ y,
                                                 unsigned short* __restrict__ S2T) {
  __shared__ unsigned short tx[64][72];
  __shared__ unsigned short ty[64][72];
  const int t = threadIdx.x;
  const int r = t >> 2, q = t & 3;
  const int gj = blockIdx.y * 64 + r;
  const int gf0 = blockIdx.x * 64;
#pragma unroll
  for (int i = 0; i < 4; ++i) {
    int c = q * 4 + i * 16;
    float4 vx = *(const float4*)&x[(size_t)gj * N_FEAT + gf0 + c];
    float4 vy = *(const float4*)&y[(size_t)gj * N_FEAT + gf0 + c];
    tx[c + 0][r] = f2bf(vx.x); tx[c + 1][r] = f2bf(vx.y);
    tx[c + 2][r] = f2bf(vx.z); tx[c + 3][r] = f2bf(vx.w);
    ty[c + 0][r] = f2bf(vy.x); ty[c + 1][r] = f2bf(vy.y);
    ty[c + 2][r] = f2bf(vy.z); ty[c + 3][r] = f2bf(vy.w);
  }
  __syncthreads();
  const int f2 = t >> 2;
#pragma unroll
  for (int j = 0; j < 2; ++j) {
    int js = q * 8 + j * 32;
    ushort8v ux = *(const ushort8v*)&tx[f2][js];
    ushort8v uy = *(const ushort8v*)&ty[f2][js];
    *(ushort8v*)&S2T[(size_t)(2 * (gf0 + f2) + 0) * N_NODES + blockIdx.y * 64 + js] = ux;
    *(ushort8v*)&S2T[(size_t)(2 * (gf0 + f2) + 1) * N_NODES + blockIdx.y * 64 + js] = uy;
  }
}

// --------------------------------------------------------------- split-K GEMM
// BM=128, BN=64, BK=64, 256 threads (4 waves 2x2), wave tile 64x32.
// 1-D grid of 1024 blocks; XCD-bijective remap: xcd=L%8 owns contiguous (mtile,z)
// panel-groups; its 2^NTB ntile-sharers are co-resident -> A-panel fetched once.
// LDS: linear dest (global_load_lds), XOR slot-swizzle via pre-swizzled global src:
// LDS[row][slot] holds global k-slot (slot ^ (row&7)); ds_read applies same XOR.
template <int NTB>
__global__ __launch_bounds__(256, 4) void gemm_swz(const unsigned short* __restrict__ A,
                                                   const unsigned short* __restrict__ B,
                                                   float* __restrict__ part,
                                                   int K, int Kc, int Nn, size_t MN) {
  __shared__ unsigned short As[128 * 64];
  __shared__ unsigned short Bs[64 * 64];
  const int t = threadIdx.x;
  const int lane = t & 63, w = t >> 6;

  const unsigned L = blockIdx.x;
  const unsigned cx = L & 7u, j = L >> 3;
  const unsigned ntile = j & ((1u << NTB) - 1u);
  const unsigned group = cx * (128u >> NTB) + (j >> NTB);  // [0, 128*8>>... ) bijective
  const unsigned mtile = group & 31u;
  const unsigned zz = group >> 5u;

  const int wr = (w >> 1) * 64;
  const int wc = (w & 1) * 32;
  const int l15 = lane & 15;
  const int lhi = lane >> 4;

  const size_t kbase = (size_t)zz * Kc;
  // pre-swizzled per-lane source offset (bytes): row lane>>3, k-slot (lane&7)^(lane>>3)
  const size_t srcoff = (size_t)(lane >> 3) * K * 2 + (size_t)(((lane & 7) ^ (lane >> 3)) << 4);

  const char* Ag = (const char*)(A + (size_t)mtile * 128 * K + kbase);
  const char* Bg = (const char*)(B + (size_t)ntile * 64 * K + kbase);

  f32x4 acc[4][2];
#pragma unroll
  for (int mi = 0; mi < 4; ++mi)
#pragma unroll
    for (int ni = 0; ni < 2; ++ni) acc[mi][ni] = (f32x4){0.f, 0.f, 0.f, 0.f};

  const int nkt = Kc >> 6;
  for (int kt = 0; kt < nkt; ++kt) {
    const size_t ko = (size_t)kt * 128;  // BK=64 bf16 = 128 B
#pragma unroll
    for (int q = 0; q < 4; ++q)
      gload_lds16(Ag + (size_t)(w * 4 + q) * 8 * K * 2 + srcoff + ko, &As[(w * 4 + q) * 512]);
#pragma unroll
    for (int q = 0; q < 2; ++q)
      gload_lds16(Bg + (size_t)(w * 2 + q) * 8 * K * 2 + srcoff + ko, &Bs[(w * 2 + q) * 512]);
    __syncthreads();
    short8 a[4][2], b[2][2];
#pragma unroll
    for (int mi = 0; mi < 4; ++mi) {
      const int ar = wr + mi * 16 + l15;
#pragma unroll
      for (int ks = 0; ks < 2; ++ks)
        a[mi][ks] = *(const short8*)((const char*)As + (size_t)ar * 128 +
                                     ((((ks << 2) | lhi) ^ (ar & 7)) << 4));
    }
#pragma unroll
    for (int ni = 0; ni < 2; ++ni) {
      const int br = wc + ni * 16 + l15;
#pragma unroll
      for (int ks = 0; ks < 2; ++ks)
        b[ni][ks] = *(const short8*)((const char*)Bs + (size_t)br * 128 +
                                     ((((ks << 2) | lhi) ^ (br & 7)) << 4));
    }
#pragma unroll
    for (int ks = 0; ks < 2; ++ks)
#pragma unroll
      for (int mi = 0; mi < 4; ++mi)
#pragma unroll
        for (int ni = 0; ni < 2; ++ni)
          acc[mi][ni] = __builtin_amdgcn_mfma_f32_16x16x32_bf16(a[mi][ks], b[ni][ks],
                                                                acc[mi][ni], 0, 0, 0);
    __syncthreads();
  }

  float* po = part + (size_t)zz * MN;
  const int m0 = mtile * 128 + wr + lhi * 4;
  const int n0 = ntile * 64 + wc + l15;
#pragma unroll
  for (int mi = 0; mi < 4; ++mi)
#pragma unroll
    for (int ni = 0; ni < 2; ++ni)
#pragma unroll
      for (int r = 0; r < 4; ++r)
        po[(size_t)(m0 + mi * 16 + r) * Nn + n0 + ni * 16] = acc[mi][ni][r];
}

// --------------- reduce1: Zt[f][m] = c[m]*sum_ks part[ks][m][2f] + p2[m]*sum_ks part[ks][m][2f+1]
__global__ __launch_bounds__(256) void reduce1_k(const float* __restrict__ part,
                                                 const float* __restrict__ cbuf,
                                                 const float* __restrict__ p2buf,
                                                 unsigned short* __restrict__ Zt) {
  __shared__ unsigned short zt[64][72];
  const int t = threadIdx.x;
  const int r = t >> 2, q = t & 3;
  const int m = blockIdx.y * 64 + r;
  const int n0 = blockIdx.x * 128;
  const float cv = cbuf[m], pv = p2buf[m];
  float acc[16];
#pragma unroll
  for (int i = 0; i < 16; ++i) acc[i] = 0.f;
  for (int ks = 0; ks < 4; ++ks) {
    const float* p = part + ((size_t)ks * N_NODES + m) * 512 + n0;
#pragma unroll
    for (int i = 0; i < 8; ++i) {
      float4 v = *(const float4*)&p[q * 4 + i * 16];  // (x_f, y_f, x_{f+1}, y_{f+1})
      acc[2 * i + 0] += cv * v.x + pv * v.y;
      acc[2 * i + 1] += cv * v.z + pv * v.w;
    }
  }
#pragma unroll
  for (int i = 0; i < 8; ++i) {
    int f = q * 2 + i * 8;
    zt[f + 0][r] = f2bf(acc[2 * i + 0]);
    zt[f + 1][r] = f2bf(acc[2 * i + 1]);
  }
  __syncthreads();
  const int f2 = t >> 2;
  const int gf = blockIdx.x * 64 + f2;
#pragma unroll
  for (int w = 0; w < 2; ++w) {
    int js = q * 8 + w * 32;
    ushort8v u = *(const ushort8v*)&zt[f2][js];
    *(ushort8v*)&Zt[(size_t)gf * N_NODES + blockIdx.y * 64 + js] = u;
  }
}

// --------------- reduce2: out[e] = sum_{ks<8} part[ks][e]
__global__ __launch_bounds__(256) void reduce2_k(const float* __restrict__ part,
                                                 float* __restrict__ out) {
  const size_t e = ((size_t)blockIdx.x * 256 + threadIdx.x) * 4;
  float4 s = {0.f, 0.f, 0.f, 0.f};
#pragma unroll
  for (int ks = 0; ks < 8; ++ks) {
    float4 v = *(const float4*)&part[(size_t)ks * N_NODES * N_FEAT + e];
    s.x += v.x; s.y += v.y; s.z += v.z; s.w += v.w;
  }
  *(float4*)&out[e] = s;
}

extern "C" void kernel_launch(void* const* d_in, const int* in_sizes, int n_in,
                              void* d_out, int out_size, void* d_ws, size_t ws_size,
                              hipStream_t stream) {
  const float* x   = (const float*)d_in[0];
  const float* y   = (const float*)d_in[1];
  const float* tp  = (const float*)d_in[2];
  const float* lam = (const float*)d_in[3];
  const float* V   = (const float*)d_in[4];

  char* w = (char*)d_ws;
  unsigned short* Vbf  = (unsigned short*)w; w += (size_t)N_NODES * N_NODES * 2;
  unsigned short* Vtbf = (unsigned short*)w; w += (size_t)N_NODES * N_NODES * 2;
  unsigned short* S2T  = (unsigned short*)w; w += (size_t)512 * N_NODES * 2;
  unsigned short* Zt   = (unsigned short*)w; w += (size_t)N_FEAT * N_NODES * 2;
  float* cbuf  = (float*)w; w += N_NODES * 4;
  float* p2buf = (float*)w; w += N_NODES * 4;
  float* partb = (float*)w; w += (size_t)4 * N_NODES * 512 * 4;  // 32MB, shared by both stages

  spectrum_k<<<N_NODES / 256, 256, 0, stream>>>(lam, tp, cbuf, p2buf);
  prep_v_k<<<dim3(N_NODES / 64, N_NODES / 64), 256, 0, stream>>>(V, Vbf, Vtbf);
  prep_xy_k<<<dim3(N_FEAT / 64, N_NODES / 64), 256, 0, stream>>>(x, y, S2T);
  // GEMM1: part[z][i][s] = Vt[i, z-chunk] . S2T[s, z-chunk]   (z=4, Kc=1024, NTB=3: 8 ntiles)
  gemm_swz<3><<<1024, 256, 0, stream>>>(Vtbf, S2T, partb, N_NODES, 1024, 512,
                                        (size_t)N_NODES * 512);
  reduce1_k<<<dim3(512 / 128, N_NODES / 64), 256, 0, stream>>>(partb, cbuf, p2buf, Zt);
  // GEMM2: part[z][j][f] = Vbf[j, z-chunk] . Zt[f, z-chunk]   (z=8, Kc=512, NTB=2: 4 ntiles)
  gemm_swz<2><<<1024, 256, 0, stream>>>(Vbf, Zt, partb, N_NODES, 512, N_FEAT,
                                        (size_t)N_NODES * N_FEAT);
  reduce2_k<<<(N_NODES * N_FEAT) / 1024, 256, 0, stream>>>(partb, (float*)d_out);
}